// Round 9
// baseline (1289.495 us; speedup 1.0000x reference)
//
#include <hip/hip_runtime.h>
#include <math.h>

// SidNet signed diffusion, S/D-decoupled bf16 state, feature-chunk x XCD sharding.
// Round 8 resubmit (prior run died to container infra twice, no counters; the
// identical situation in r5->r6 resolved on resubmission; kernel audit clean).
// Rolling gather pipeline in the layer kernel (traffic path = r7):
//   Diagnosis r0-r7: VALU busy-time constant ~29us while dur 87-124us; no
//   throughput wall near (TCP ~16us, L2-BW ~18us, fabric ~39us @155MB). The
//   binder is gather latency x insufficient sustained MLP: each 16-gather
//   body drains vmcnt 16->0 during its FMA phase, then stalls through the
//   next body's LDS publish/read. Fix: merge "consume body k" with "issue
//   body k+1" slot-by-slot (w[i] WAR-recycled), so every FMA waits at a
//   constant vmcnt(~16) and 16 gathers stay in flight continuously. The
//   publish + edge-prefetch + recs-read for body k+1 are hoisted before the
//   merged loop. w[16]/rec[16] fully unrolled, constant-indexed (regs).
// Keeps r7: 4B edge records (u16 col|bf16 val), nt edge loads + LDS broadcast
// (TCP lookups/edge 1.125), cached Out/tX, degree-sorted perm, chunk=blockIdx&7
// XCD pinning (In slice 3.2MB/XCD).

#define TB 256

__device__ __forceinline__ unsigned pack_bf16(float a, float b) {
    unsigned ua = __float_as_uint(a), ub = __float_as_uint(b);
    ua += 0x7fffu + ((ua >> 16) & 1u);   // RNE
    ub += 0x7fffu + ((ub >> 16) & 1u);
    return (ua >> 16) | (ub & 0xffff0000u);
}

__device__ __forceinline__ float2 unpack_bf16(unsigned w) {
    float2 r;
    r.x = __uint_as_float(w << 16);
    r.y = __uint_as_float(w & 0xffff0000u);
    return r;
}

__global__ void zero_int_kernel(int* __restrict__ p, int n) {
    int i = blockIdx.x * blockDim.x + threadIdx.x;
    if (i < n) p[i] = 0;
}

// K1: bucket histogram (bucket = row>>9), LDS-staged to keep global atomics rare.
__global__ void bucket_count_kernel(const int* __restrict__ rows_p,
                                    const int* __restrict__ rows_m,
                                    int E, int* __restrict__ bcnt) {
    __shared__ int h[128];
    for (int i = threadIdx.x; i < 128; i += TB) h[i] = 0;
    __syncthreads();
    int total = 2 * E;
    for (int e = blockIdx.x * TB + threadIdx.x; e < total; e += gridDim.x * TB) {
        int r = (e < E) ? rows_p[e] : rows_m[e - E];
        atomicAdd(&h[r >> 9], 1);
    }
    __syncthreads();
    for (int i = threadIdx.x; i < 128; i += TB)
        if (h[i]) atomicAdd(&bcnt[i], h[i]);
}

// K2: single-wave exclusive scan of 128 bucket counts -> boff[0..128], bcur copy.
__global__ void bucket_scan_kernel(const int* __restrict__ bcnt,
                                   int* __restrict__ boff, int* __restrict__ bcur) {
    int l = threadIdx.x;              // 0..63
    int v0 = bcnt[l], v1 = bcnt[l + 64];
    int i0 = v0, i1 = v1;
#pragma unroll
    for (int o = 1; o < 64; o <<= 1) { int y = __shfl_up(i0, o); if (l >= o) i0 += y; }
#pragma unroll
    for (int o = 1; o < 64; o <<= 1) { int y = __shfl_up(i1, o); if (l >= o) i1 += y; }
    int t0 = __shfl(i0, 63);          // total of low half
    int e0 = i0 - v0;
    int e1 = i1 - v1 + t0;
    boff[l] = e0;      boff[l + 64] = e1;
    bcur[l] = e0;      bcur[l + 64] = e1;
    if (l == 63) boff[128] = i1 + t0; // grand total = 2E
}

// K3: tile-local bucket sort in LDS, then coalesced run-writes to stage[].
__global__ __launch_bounds__(TB) void partition_kernel(
    const int* __restrict__ rows_p, const int* __restrict__ cols_p,
    const float* __restrict__ vals_p,
    const int* __restrict__ rows_m, const int* __restrict__ cols_m,
    const float* __restrict__ vals_m, int E,
    int* __restrict__ bcur_g, uint2* __restrict__ stage) {
    __shared__ unsigned keys[2048];
    __shared__ float    vals[2048];
    __shared__ unsigned skeys[2048];
    __shared__ float    svals[2048];
    __shared__ int h[128], boff[128], bcur[128], bbase[128];
    int tile0 = blockIdx.x * 2048;
    int cnt = min(2048, 2 * E - tile0);

    for (int i = threadIdx.x; i < cnt; i += TB) {
        int e = tile0 + i; int r, c; float v;
        if (e < E) { r = rows_p[e]; c = cols_p[e]; v = vals_p[e]; }
        else       { r = rows_m[e - E]; c = cols_m[e - E]; v = -vals_m[e - E]; }
        keys[i] = ((unsigned)r << 16) | (unsigned)c;
        vals[i] = v;
    }
    for (int i = threadIdx.x; i < 128; i += TB) { h[i] = 0; bcur[i] = 0; }
    __syncthreads();
    for (int i = threadIdx.x; i < cnt; i += TB) atomicAdd(&h[keys[i] >> 25], 1);
    __syncthreads();
    if (threadIdx.x < 64) {           // wave 0: scan 128 counters
        int l = threadIdx.x;
        int v0 = h[l], v1 = h[l + 64], i0 = v0, i1 = v1;
#pragma unroll
        for (int o = 1; o < 64; o <<= 1) { int y = __shfl_up(i0, o); if (l >= o) i0 += y; }
#pragma unroll
        for (int o = 1; o < 64; o <<= 1) { int y = __shfl_up(i1, o); if (l >= o) i1 += y; }
        int t0 = __shfl(i0, 63);
        boff[l] = i0 - v0;
        boff[l + 64] = i1 - v1 + t0;
    }
    __syncthreads();
    for (int i = threadIdx.x; i < cnt; i += TB) {
        unsigned k = keys[i]; int b = k >> 25;
        int p = boff[b] + atomicAdd(&bcur[b], 1);
        skeys[p] = k; svals[p] = vals[i];
    }
    __syncthreads();
    if (threadIdx.x < 128) {
        int c_ = h[threadIdx.x];
        if (c_) bbase[threadIdx.x] = atomicAdd(&bcur_g[threadIdx.x], c_);
    }
    __syncthreads();
    for (int i = threadIdx.x; i < cnt; i += TB) {
        unsigned k = skeys[i]; int b = k >> 25;
        stage[bbase[b] + (i - boff[b])] = make_uint2(k, __float_as_uint(svals[i]));
    }
}

// K4: one block per bucket (512 rows). LDS row-histogram + scan -> off[],
// then scatter 4B records (u16 col | bf16 val) into the bucket's CSR range.
__global__ __launch_bounds__(TB) void csr_finalize_kernel(
    const uint2* __restrict__ stage, const int* __restrict__ boff_g,
    int NBv, int N, int E2, int* __restrict__ off, unsigned* __restrict__ edge) {
    __shared__ int rc[512], ro[512], rcur[512];
    int b = blockIdx.x;
    int row0 = b << 9;
    int s0 = boff_g[b], s1 = boff_g[b + 1];
    for (int i = threadIdx.x; i < 512; i += TB) { rc[i] = 0; rcur[i] = 0; }
    __syncthreads();
    for (int i = s0 + threadIdx.x; i < s1; i += TB)
        atomicAdd(&rc[(stage[i].x >> 16) - row0], 1);
    __syncthreads();
    if (threadIdx.x < 64) {           // wave 0: exclusive scan of 512 counts
        int l = threadIdx.x;
        int s = 0, loc[8];
#pragma unroll
        for (int j = 0; j < 8; ++j) { loc[j] = s; s += rc[l * 8 + j]; }
        int incl = s;
#pragma unroll
        for (int o = 1; o < 64; o <<= 1) { int y = __shfl_up(incl, o); if (l >= o) incl += y; }
        int base = incl - s;
#pragma unroll
        for (int j = 0; j < 8; ++j) ro[l * 8 + j] = base + loc[j];
    }
    __syncthreads();
    for (int i = threadIdx.x; i < 512; i += TB) {
        int r = row0 + i;
        if (r < N) off[r] = s0 + ro[i];
    }
    if (b == NBv - 1 && threadIdx.x == 0) off[N] = E2;
    for (int i = s0 + threadIdx.x; i < s1; i += TB) {
        uint2 rec = stage[i];
        int lr = (int)(rec.x >> 16) - row0;
        int p = s0 + ro[lr] + atomicAdd(&rcur[lr], 1);
        unsigned vb = pack_bf16(0.f, __uint_as_float(rec.y)) & 0xffff0000u;
        edge[p] = (rec.x & 0xffffu) | vb;
    }
}

// D1: degree histogram (bins 0..511, clamped), LDS-staged.
__global__ void deg_hist_kernel(const int* __restrict__ off, int N,
                                int* __restrict__ dhist) {
    __shared__ int h[512];
    for (int i = threadIdx.x; i < 512; i += TB) h[i] = 0;
    __syncthreads();
    for (int r = blockIdx.x * TB + threadIdx.x; r < N; r += gridDim.x * TB) {
        int d = off[r + 1] - off[r];
        if (d > 511) d = 511;
        atomicAdd(&h[d], 1);
    }
    __syncthreads();
    for (int i = threadIdx.x; i < 512; i += TB)
        if (h[i]) atomicAdd(&dhist[i], h[i]);
}

// D2: single-wave exclusive scan of 512 degree bins -> dcur (running cursors).
__global__ void deg_scan_kernel(const int* __restrict__ dhist,
                                int* __restrict__ dcur) {
    int l = threadIdx.x;              // 0..63
    int s = 0, loc[8];
#pragma unroll
    for (int j = 0; j < 8; ++j) { loc[j] = s; s += dhist[l * 8 + j]; }
    int incl = s;
#pragma unroll
    for (int o = 1; o < 64; o <<= 1) { int y = __shfl_up(incl, o); if (l >= o) incl += y; }
    int base = incl - s;
#pragma unroll
    for (int j = 0; j < 8; ++j) dcur[l * 8 + j] = base + loc[j];
}

// D3: scatter rows into degree-sorted perm[] (block-staged).
__global__ __launch_bounds__(TB) void deg_scatter_kernel(
    const int* __restrict__ off, int N, int* __restrict__ dcur,
    int* __restrict__ perm) {
    __shared__ int h[512], lbase[512], lcur[512];
    int r = blockIdx.x * TB + threadIdx.x;
    int d = -1;
    if (r < N) { d = off[r + 1] - off[r]; if (d > 511) d = 511; }
    for (int i = threadIdx.x; i < 512; i += TB) { h[i] = 0; lcur[i] = 0; }
    __syncthreads();
    if (d >= 0) atomicAdd(&h[d], 1);
    __syncthreads();
    for (int i = threadIdx.x; i < 512; i += TB)
        if (h[i]) lbase[i] = atomicAdd(&dcur[i], h[i]);
    __syncthreads();
    if (d >= 0) {
        int p = lbase[d] + atomicAdd(&lcur[d], 1);
        perm[p] = r;
    }
}

// Init, chunk-major: thread i -> row r=i>>5, feature-quad q5=i&31.
__global__ void init_kernel(const float* __restrict__ X, const float* __restrict__ M0,
                            uint2* __restrict__ SD, uint2* __restrict__ tXb,
                            int n32, int N) {
    int i = blockIdx.x * blockDim.x + threadIdx.x;
    if (i < n32) {
        int r = i >> 5, q5 = i & 31;
        int c = q5 >> 2, q = q5 & 3;
        float4 x = ((const float4*)X)[(size_t)r * 32 + q5];
        float4 m = ((const float4*)M0)[(size_t)r * 32 + q5];
        size_t rb = (size_t)c * N + r;
        SD[rb * 8 + q]     = make_uint2(pack_bf16(x.x + m.x, x.y + m.y),
                                        pack_bf16(x.z + m.z, x.w + m.w));
        SD[rb * 8 + 4 + q] = make_uint2(pack_bf16(x.x - m.x, x.y - m.y),
                                        pack_bf16(x.z - m.z, x.w - m.w));
        tXb[rb * 4 + q]    = make_uint2(pack_bf16(0.15f * x.x, 0.15f * x.y),
                                        pack_bf16(0.15f * x.z, 0.15f * x.w));
    }
}

// Layer: block -> (chunk c = blockIdx&7, wave-block = blockIdx>>3).
// Wave = 8 subgroups x 8 slots; subgroup owns row perm[wave*8+sub].
// Rolling gather pipeline over 16-edge bodies:
//   prologue: publish body0, read rec[16], issue gathers w[16];
//   loop (while body k+1 exists):
//     publish body k+1 (edges prefetched in iter k-1), nt-prefetch body k+2,
//     ds_read recn[16]; then interleaved x16: FMA(w[i],rec[i]) ; w[i]=gather
//     (recn[i]) ; rec[i]=recn[i].  Every FMA waits at a constant vmcnt(~16):
//     16 gathers stay in flight through the FMA phase (WAR recycling of w[i]).
//   epilogue: FMA last in-flight body; then simple <16-edge tail.
// nt only on edge loads; Out/tX normal cached.
__global__ __launch_bounds__(TB) void layer_kernel(
    const int* __restrict__ off, const unsigned* __restrict__ edge,
    const int* __restrict__ perm,
    const uint2* __restrict__ In, uint2* __restrict__ Out,
    const uint2* __restrict__ tXb,
    float* __restrict__ Pout, float* __restrict__ Mout, int last, int N) {
    __shared__ unsigned ebuf[4][8][17];
    int c = blockIdx.x & 7;
    int wid = threadIdx.x >> 6;
    int wave = (blockIdx.x >> 3) * 4 + wid;
    int lane = threadIdx.x & 63;
    int slot = lane & 7;
    int sub  = lane >> 3;
    int sys  = slot >> 2;
    int q    = slot & 3;
    unsigned vmaskhi = sys ? 0xffff0000u : 0x7fff0000u;

    int idx = wave * 8 + sub;
    bool valid = idx < N;
    int row = 0;
    if (valid) row = perm[idx];

    const uint2* Inc  = In  + (size_t)c * N * 8;
    uint2*       Outc = Out + (size_t)c * N * 8;
    const uint2* tXc  = tXb + (size_t)c * N * 4;

    unsigned* eb = ebuf[wid][sub];

    int bg = 0, en = 0;
    float a0 = 0.f, a1 = 0.f, a2 = 0.f, a3 = 0.f;
    if (valid) {
        bg = off[row]; en = off[row + 1];
        uint2 t = tXc[(size_t)row * 4 + q];          // normal cached
        float2 t0 = unpack_bf16(t.x);
        float2 t1 = unpack_bf16(t.y);
        a0 = t0.x; a1 = t0.y; a2 = t1.x; a3 = t1.y;
    }

    int j = bg;
    if (j + 16 <= en) {
        // --- prologue: body 0 ---
        unsigned r0 = __builtin_nontemporal_load(&edge[j + slot]);
        unsigned r1 = __builtin_nontemporal_load(&edge[j + 8 + slot]);
        eb[slot]     = r0;
        eb[8 + slot] = r1;
        int jn = j + 16;
        unsigned r0n = 0, r1n = 0;
        if (jn + 16 <= en) {                  // prefetch body 1
            r0n = __builtin_nontemporal_load(&edge[jn + slot]);
            r1n = __builtin_nontemporal_load(&edge[jn + 8 + slot]);
        }
        unsigned rec[16];
        uint2 w[16];
#pragma unroll
        for (int i = 0; i < 16; ++i) rec[i] = eb[i];
#pragma unroll
        for (int i = 0; i < 16; ++i)
            w[i] = Inc[(size_t)(rec[i] & 0xffffu) * 8 + slot];
        // --- main pipelined loop: consume body k, issue body k+1 ---
        for (; jn + 16 <= en; ) {
            eb[slot]     = r0n;               // publish body k+1
            eb[8 + slot] = r1n;
            int jn2 = jn + 16;
            if (jn2 + 16 <= en) {             // prefetch body k+2
                r0n = __builtin_nontemporal_load(&edge[jn2 + slot]);
                r1n = __builtin_nontemporal_load(&edge[jn2 + 8 + slot]);
            }
            unsigned recn[16];
#pragma unroll
            for (int i = 0; i < 16; ++i) recn[i] = eb[i];
#pragma unroll
            for (int i = 0; i < 16; ++i) {
                float v = __uint_as_float(rec[i] & vmaskhi);
                float2 ga = unpack_bf16(w[i].x), gb = unpack_bf16(w[i].y);
                a0 += v * ga.x; a1 += v * ga.y; a2 += v * gb.x; a3 += v * gb.y;
                w[i] = Inc[(size_t)(recn[i] & 0xffffu) * 8 + slot];  // WAR recycle
                rec[i] = recn[i];
            }
            jn = jn2;
        }
        // --- epilogue: consume last in-flight body ---
#pragma unroll
        for (int i = 0; i < 16; ++i) {
            float v = __uint_as_float(rec[i] & vmaskhi);
            float2 ga = unpack_bf16(w[i].x), gb = unpack_bf16(w[i].y);
            a0 += v * ga.x; a1 += v * ga.y; a2 += v * gb.x; a3 += v * gb.y;
        }
        j = jn;
    }
    int cnt = en - j;
    if (cnt > 0) {                            // masked tail body (<=15 edges)
        if (slot < cnt)     eb[slot]     = __builtin_nontemporal_load(&edge[j + slot]);
        if (8 + slot < cnt) eb[8 + slot] = __builtin_nontemporal_load(&edge[j + 8 + slot]);
        for (int i = 0; i < cnt; ++i) {
            unsigned rec = eb[i];
            int col = rec & 0xffffu;
            uint2 w = Inc[(size_t)col * 8 + slot];
            float v = __uint_as_float(rec & vmaskhi);
            float2 ga = unpack_bf16(w.x), gb = unpack_bf16(w.y);
            a0 += v * ga.x; a1 += v * ga.y; a2 += v * gb.x; a3 += v * gb.y;
        }
    }

    if (!last) {
        if (valid)                             // normal cached store
            Outc[(size_t)row * 8 + slot] =
                make_uint2(pack_bf16(a0, a1), pack_bf16(a2, a3));
    } else {
        // pair S/D within subgroup: lane^4 holds the other system, same quad
        float b0 = __shfl_xor(a0, 4), b1 = __shfl_xor(a1, 4);
        float b2 = __shfl_xor(a2, 4), b3 = __shfl_xor(a3, 4);
        if (valid) {
            if (sys == 0) {   // P = (S+D)/2
                ((float4*)Pout)[(size_t)row * 32 + 4 * c + q] =
                    make_float4(0.5f * (a0 + b0), 0.5f * (a1 + b1),
                                0.5f * (a2 + b2), 0.5f * (a3 + b3));
            } else {          // M = (S-D)/2, here a=D, b=S
                ((float4*)Mout)[(size_t)row * 32 + 4 * c + q] =
                    make_float4(0.5f * (b0 - a0), 0.5f * (b1 - a1),
                                0.5f * (b2 - a2), 0.5f * (b3 - a3));
            }
        }
    }
}

extern "C" void kernel_launch(void* const* d_in, const int* in_sizes, int n_in,
                              void* d_out, int out_size, void* d_ws, size_t ws_size,
                              hipStream_t stream) {
    const int*   rows_p = (const int*)d_in[0];
    const int*   cols_p = (const int*)d_in[1];
    const float* vals_p = (const float*)d_in[2];
    const int*   rows_m = (const int*)d_in[3];
    const int*   cols_m = (const int*)d_in[4];
    const float* vals_m = (const float*)d_in[5];
    const float* X      = (const float*)d_in[6];
    const float* M0     = (const float*)d_in[7];

    const int E = in_sizes[0];
    const int D = 128;
    const int N = in_sizes[6] / D;       // 50000 (<65536: 16-bit r/c packing ok)
    const int K = 10;
    const int E2 = 2 * E;
    const size_t ND = (size_t)N * D;
    const int N32 = N * 32;
    const int NBv = (N + 511) >> 9;      // buckets of 512 rows, <=128

    float* outP = (float*)d_out;
    float* outM = outP + ND;

    char* ws = (char*)d_ws;
    size_t o = 0;
    auto alloc = [&](size_t b) -> void* {
        void* p = ws + o;
        o += (b + 255) & ~(size_t)255;
        return p;
    };
    uint2*    SDA  = (uint2*)alloc((size_t)N * 64 * 8);
    uint2*    SDB  = (uint2*)alloc((size_t)N * 64 * 8);
    uint2*    tXb  = (uint2*)alloc((size_t)N * 32 * 8);
    int*      off  = (int*)alloc((size_t)(N + 1) * sizeof(int));
    unsigned* edge = (unsigned*)alloc((size_t)E2 * sizeof(unsigned));
    int*      bcnt = (int*)alloc(128 * sizeof(int));
    int*      boff = (int*)alloc(129 * sizeof(int));
    int*      bcur = (int*)alloc(128 * sizeof(int));
    int*      dhist= (int*)alloc(512 * sizeof(int));
    int*      dcur = (int*)alloc(512 * sizeof(int));
    int*      perm = (int*)alloc((size_t)N * sizeof(int));
    // stage aliases SDB: consumed by csr_finalize before layer 0 writes SDB.
    uint2* stage = SDB;

    int gN32 = (N32 + TB - 1) / TB;
    int gTiles = (E2 + 2047) / 2048;

    // --- CSR build: bucket partition with LDS write-combining ---
    zero_int_kernel<<<1, 128, 0, stream>>>(bcnt, 128);
    zero_int_kernel<<<2, TB, 0, stream>>>(dhist, 512);
    bucket_count_kernel<<<512, TB, 0, stream>>>(rows_p, rows_m, E, bcnt);
    bucket_scan_kernel<<<1, 64, 0, stream>>>(bcnt, boff, bcur);
    partition_kernel<<<gTiles, TB, 0, stream>>>(rows_p, cols_p, vals_p,
                                                rows_m, cols_m, vals_m, E,
                                                bcur, stage);
    csr_finalize_kernel<<<NBv, TB, 0, stream>>>(stage, boff, NBv, N, E2, off, edge);

    // --- degree-sorted row permutation ---
    deg_hist_kernel<<<256, TB, 0, stream>>>(off, N, dhist);
    deg_scan_kernel<<<1, 64, 0, stream>>>(dhist, dcur);
    deg_scatter_kernel<<<(N + TB - 1) / TB, TB, 0, stream>>>(off, N, dcur, perm);

    // --- init chunk-major bf16 state ---
    init_kernel<<<gN32, TB, 0, stream>>>(X, M0, SDA, tXb, N32, N);

    // --- K layers, ping-pong; chunk = blockIdx&7 pins chunk to XCD ---
    int nWaves = (N + 7) >> 3;           // 8 rows per wave (1 per subgroup)
    int bpc = (nWaves + 3) >> 2;         // 4 waves per block
    int gL = bpc * 8;
    uint2 *Si = SDA, *So = SDB;
    for (int k = 0; k < K; ++k) {
        int last = (k == K - 1);
        layer_kernel<<<gL, TB, 0, stream>>>(off, edge, perm, Si, So, tXb,
                                            outP, outM, last, N);
        uint2* t = Si; Si = So; So = t;
    }
}

// Round 10
// 981.676 us; speedup vs baseline: 1.3136x; 1.3136x over previous
//
#include <hip/hip_runtime.h>
#include <math.h>

// SidNet signed diffusion, S/D-decoupled + bf16 interleaved state.
// Round 10: RETURN to the round-0 proven structure (one row per 64-lane wave,
// 512B coalesced In gathers, 8-deep unroll; 87us/layer @ 3.78 TB/s fabric --
// the best measured across 9 restructuring rounds; every 64B-granule chunked
// variant was latency-pinned at 117-124us despite lower traffic).
// One structure-preserving cut vs r0: 4B edge records (u16 col | bf16 val),
// proven numerically safe in r4-r9 (same absmax, passed). Halves the edge
// stream (9.6->4.8MB/layer) and replaces int_as_float+fabsf with one AND.
// Degree-sort kernels dropped (not used by this layer structure).

#define TB 256

__device__ __forceinline__ unsigned pack_bf16(float a, float b) {
    unsigned ua = __float_as_uint(a), ub = __float_as_uint(b);
    ua += 0x7fffu + ((ua >> 16) & 1u);   // RNE
    ub += 0x7fffu + ((ub >> 16) & 1u);
    return (ua >> 16) | (ub & 0xffff0000u);
}

__device__ __forceinline__ float2 unpack_bf16(unsigned w) {
    float2 r;
    r.x = __uint_as_float(w << 16);
    r.y = __uint_as_float(w & 0xffff0000u);
    return r;
}

__global__ void zero_int_kernel(int* __restrict__ p, int n) {
    int i = blockIdx.x * blockDim.x + threadIdx.x;
    if (i < n) p[i] = 0;
}

// K1: bucket histogram (bucket = row>>9), LDS-staged to keep global atomics rare.
__global__ void bucket_count_kernel(const int* __restrict__ rows_p,
                                    const int* __restrict__ rows_m,
                                    int E, int* __restrict__ bcnt) {
    __shared__ int h[128];
    for (int i = threadIdx.x; i < 128; i += TB) h[i] = 0;
    __syncthreads();
    int total = 2 * E;
    for (int e = blockIdx.x * TB + threadIdx.x; e < total; e += gridDim.x * TB) {
        int r = (e < E) ? rows_p[e] : rows_m[e - E];
        atomicAdd(&h[r >> 9], 1);
    }
    __syncthreads();
    for (int i = threadIdx.x; i < 128; i += TB)
        if (h[i]) atomicAdd(&bcnt[i], h[i]);
}

// K2: single-wave exclusive scan of 128 bucket counts -> boff[0..128], bcur copy.
__global__ void bucket_scan_kernel(const int* __restrict__ bcnt,
                                   int* __restrict__ boff, int* __restrict__ bcur) {
    int l = threadIdx.x;              // 0..63
    int v0 = bcnt[l], v1 = bcnt[l + 64];
    int i0 = v0, i1 = v1;
#pragma unroll
    for (int o = 1; o < 64; o <<= 1) { int y = __shfl_up(i0, o); if (l >= o) i0 += y; }
#pragma unroll
    for (int o = 1; o < 64; o <<= 1) { int y = __shfl_up(i1, o); if (l >= o) i1 += y; }
    int t0 = __shfl(i0, 63);          // total of low half
    int e0 = i0 - v0;
    int e1 = i1 - v1 + t0;
    boff[l] = e0;      boff[l + 64] = e1;
    bcur[l] = e0;      bcur[l + 64] = e1;
    if (l == 63) boff[128] = i1 + t0; // grand total = 2E
}

// K3: tile-local bucket sort in LDS, then coalesced run-writes to stage[].
__global__ __launch_bounds__(TB) void partition_kernel(
    const int* __restrict__ rows_p, const int* __restrict__ cols_p,
    const float* __restrict__ vals_p,
    const int* __restrict__ rows_m, const int* __restrict__ cols_m,
    const float* __restrict__ vals_m, int E,
    int* __restrict__ bcur_g, uint2* __restrict__ stage) {
    __shared__ unsigned keys[2048];
    __shared__ float    vals[2048];
    __shared__ unsigned skeys[2048];
    __shared__ float    svals[2048];
    __shared__ int h[128], boff[128], bcur[128], bbase[128];
    int tile0 = blockIdx.x * 2048;
    int cnt = min(2048, 2 * E - tile0);

    for (int i = threadIdx.x; i < cnt; i += TB) {
        int e = tile0 + i; int r, c; float v;
        if (e < E) { r = rows_p[e]; c = cols_p[e]; v = vals_p[e]; }
        else       { r = rows_m[e - E]; c = cols_m[e - E]; v = -vals_m[e - E]; }
        keys[i] = ((unsigned)r << 16) | (unsigned)c;
        vals[i] = v;
    }
    for (int i = threadIdx.x; i < 128; i += TB) { h[i] = 0; bcur[i] = 0; }
    __syncthreads();
    for (int i = threadIdx.x; i < cnt; i += TB) atomicAdd(&h[keys[i] >> 25], 1);
    __syncthreads();
    if (threadIdx.x < 64) {           // wave 0: scan 128 counters
        int l = threadIdx.x;
        int v0 = h[l], v1 = h[l + 64], i0 = v0, i1 = v1;
#pragma unroll
        for (int o = 1; o < 64; o <<= 1) { int y = __shfl_up(i0, o); if (l >= o) i0 += y; }
#pragma unroll
        for (int o = 1; o < 64; o <<= 1) { int y = __shfl_up(i1, o); if (l >= o) i1 += y; }
        int t0 = __shfl(i0, 63);
        boff[l] = i0 - v0;
        boff[l + 64] = i1 - v1 + t0;
    }
    __syncthreads();
    for (int i = threadIdx.x; i < cnt; i += TB) {
        unsigned k = keys[i]; int b = k >> 25;
        int p = boff[b] + atomicAdd(&bcur[b], 1);
        skeys[p] = k; svals[p] = vals[i];
    }
    __syncthreads();
    if (threadIdx.x < 128) {
        int c_ = h[threadIdx.x];
        if (c_) bbase[threadIdx.x] = atomicAdd(&bcur_g[threadIdx.x], c_);
    }
    __syncthreads();
    // bucket-sorted LDS -> stage: consecutive i in a bucket run -> consecutive
    // global addresses; each sector is filled by one block in one burst.
    for (int i = threadIdx.x; i < cnt; i += TB) {
        unsigned k = skeys[i]; int b = k >> 25;
        stage[bbase[b] + (i - boff[b])] = make_uint2(k, __float_as_uint(svals[i]));
    }
}

// K4: one block per bucket (512 rows). LDS row-histogram + scan -> off[],
// then scatter 4B records (u16 col | bf16 val) into the bucket's CSR range.
__global__ __launch_bounds__(TB) void csr_finalize_kernel(
    const uint2* __restrict__ stage, const int* __restrict__ boff_g,
    int NBv, int N, int E2, int* __restrict__ off, unsigned* __restrict__ edge) {
    __shared__ int rc[512], ro[512], rcur[512];
    int b = blockIdx.x;
    int row0 = b << 9;
    int s0 = boff_g[b], s1 = boff_g[b + 1];
    for (int i = threadIdx.x; i < 512; i += TB) { rc[i] = 0; rcur[i] = 0; }
    __syncthreads();
    for (int i = s0 + threadIdx.x; i < s1; i += TB)
        atomicAdd(&rc[(stage[i].x >> 16) - row0], 1);
    __syncthreads();
    if (threadIdx.x < 64) {           // wave 0: exclusive scan of 512 counts
        int l = threadIdx.x;
        int s = 0, loc[8];
#pragma unroll
        for (int j = 0; j < 8; ++j) { loc[j] = s; s += rc[l * 8 + j]; }
        int incl = s;
#pragma unroll
        for (int o = 1; o < 64; o <<= 1) { int y = __shfl_up(incl, o); if (l >= o) incl += y; }
        int base = incl - s;
#pragma unroll
        for (int j = 0; j < 8; ++j) ro[l * 8 + j] = base + loc[j];
    }
    __syncthreads();
    for (int i = threadIdx.x; i < 512; i += TB) {
        int r = row0 + i;
        if (r < N) off[r] = s0 + ro[i];
    }
    if (b == NBv - 1 && threadIdx.x == 0) off[N] = E2;
    for (int i = s0 + threadIdx.x; i < s1; i += TB) {
        uint2 rec = stage[i];
        int lr = (int)(rec.x >> 16) - row0;
        int p = s0 + ro[lr] + atomicAdd(&rcur[lr], 1);
        unsigned vb = pack_bf16(0.f, __uint_as_float(rec.y)) & 0xffff0000u;
        edge[p] = (rec.x & 0xffffu) | vb;
    }
}

// Interleaved init: thread i covers row r=i>>5, quad q=i&31 (features 4q..4q+3).
__global__ void init_kernel(const float* __restrict__ X, const float* __restrict__ M0,
                            uint2* __restrict__ SD, uint2* __restrict__ tXb, int n32) {
    int i = blockIdx.x * blockDim.x + threadIdx.x;
    if (i < n32) {
        int r = i >> 5, q = i & 31;
        float4 x = ((const float4*)X)[(size_t)r * 32 + q];
        float4 m = ((const float4*)M0)[(size_t)r * 32 + q];
        SD[(size_t)r * 64 + q]      = make_uint2(pack_bf16(x.x + m.x, x.y + m.y),
                                                 pack_bf16(x.z + m.z, x.w + m.w));
        SD[(size_t)r * 64 + 32 + q] = make_uint2(pack_bf16(x.x - m.x, x.y - m.y),
                                                 pack_bf16(x.z - m.z, x.w - m.w));
        tXb[(size_t)r * 32 + q]     = make_uint2(pack_bf16(0.15f * x.x, 0.15f * x.y),
                                                 pack_bf16(0.15f * x.z, 0.15f * x.w));
    }
}

// One wave per row. lane<32: S-system (|v|); lane>=32: D-system (signed v).
// Each edge: one uint2 gather (512B coalesced across the wave) serves both
// systems. Edge records are 4B (u16 col | bf16 val): v = bits & vmaskhi
// (vmaskhi clears the sign for the S half -- replaces int_as_float+fabsf).
// last!=0: fused final -> shfl_xor(32) pairs S/D halves, write fp32 P/M.
__global__ __launch_bounds__(TB) void layer_kernel(
    const int* __restrict__ off, const unsigned* __restrict__ edge,
    const uint2* __restrict__ In, uint2* __restrict__ Out,
    const uint2* __restrict__ tXb,
    float* __restrict__ Pout, float* __restrict__ Mout, int last, int N) {
    int row = blockIdx.x * 4 + (threadIdx.x >> 6);
    if (row >= N) return;
    int lane = threadIdx.x & 63;
    int sel = lane >> 5;
    int q = lane & 31;
    unsigned vmaskhi = sel ? 0xffff0000u : 0x7fff0000u;

    uint2 t = tXb[(size_t)row * 32 + q];
    float2 t0 = unpack_bf16(t.x), t1 = unpack_bf16(t.y);
    float a0 = t0.x, a1 = t0.y, a2 = t1.x, a3 = t1.y;

    int bg = off[row], e = off[row + 1];
    int j = bg;
    for (; j + 8 <= e; j += 8) {
        unsigned e0 = edge[j],     e1 = edge[j + 1], e2 = edge[j + 2], e3 = edge[j + 3];
        unsigned e4 = edge[j + 4], e5 = edge[j + 5], e6 = edge[j + 6], e7 = edge[j + 7];
        uint2 w0 = In[(size_t)(e0 & 0xffffu) * 64 + lane];
        uint2 w1 = In[(size_t)(e1 & 0xffffu) * 64 + lane];
        uint2 w2 = In[(size_t)(e2 & 0xffffu) * 64 + lane];
        uint2 w3 = In[(size_t)(e3 & 0xffffu) * 64 + lane];
        uint2 w4 = In[(size_t)(e4 & 0xffffu) * 64 + lane];
        uint2 w5 = In[(size_t)(e5 & 0xffffu) * 64 + lane];
        uint2 w6 = In[(size_t)(e6 & 0xffffu) * 64 + lane];
        uint2 w7 = In[(size_t)(e7 & 0xffffu) * 64 + lane];
        float v0 = __uint_as_float(e0 & vmaskhi);
        float v1 = __uint_as_float(e1 & vmaskhi);
        float v2 = __uint_as_float(e2 & vmaskhi);
        float v3 = __uint_as_float(e3 & vmaskhi);
        float v4 = __uint_as_float(e4 & vmaskhi);
        float v5 = __uint_as_float(e5 & vmaskhi);
        float v6 = __uint_as_float(e6 & vmaskhi);
        float v7 = __uint_as_float(e7 & vmaskhi);
        float2 g0a = unpack_bf16(w0.x), g0b = unpack_bf16(w0.y);
        float2 g1a = unpack_bf16(w1.x), g1b = unpack_bf16(w1.y);
        float2 g2a = unpack_bf16(w2.x), g2b = unpack_bf16(w2.y);
        float2 g3a = unpack_bf16(w3.x), g3b = unpack_bf16(w3.y);
        float2 g4a = unpack_bf16(w4.x), g4b = unpack_bf16(w4.y);
        float2 g5a = unpack_bf16(w5.x), g5b = unpack_bf16(w5.y);
        float2 g6a = unpack_bf16(w6.x), g6b = unpack_bf16(w6.y);
        float2 g7a = unpack_bf16(w7.x), g7b = unpack_bf16(w7.y);
        a0 += v0 * g0a.x + v1 * g1a.x + v2 * g2a.x + v3 * g3a.x
            + v4 * g4a.x + v5 * g5a.x + v6 * g6a.x + v7 * g7a.x;
        a1 += v0 * g0a.y + v1 * g1a.y + v2 * g2a.y + v3 * g3a.y
            + v4 * g4a.y + v5 * g5a.y + v6 * g6a.y + v7 * g7a.y;
        a2 += v0 * g0b.x + v1 * g1b.x + v2 * g2b.x + v3 * g3b.x
            + v4 * g4b.x + v5 * g5b.x + v6 * g6b.x + v7 * g7b.x;
        a3 += v0 * g0b.y + v1 * g1b.y + v2 * g2b.y + v3 * g3b.y
            + v4 * g4b.y + v5 * g5b.y + v6 * g6b.y + v7 * g7b.y;
    }
    for (; j < e; ++j) {
        unsigned ed = edge[j];
        uint2 w = In[(size_t)(ed & 0xffffu) * 64 + lane];
        float v = __uint_as_float(ed & vmaskhi);
        float2 ga = unpack_bf16(w.x), gb = unpack_bf16(w.y);
        a0 += v * ga.x; a1 += v * ga.y; a2 += v * gb.x; a3 += v * gb.y;
    }

    if (!last) {
        Out[(size_t)row * 64 + lane] = make_uint2(pack_bf16(a0, a1), pack_bf16(a2, a3));
    } else {
        // pair with the other half: lane<32 holds S, lane>=32 holds D (same q)
        float b0 = __shfl_xor(a0, 32), b1 = __shfl_xor(a1, 32);
        float b2 = __shfl_xor(a2, 32), b3 = __shfl_xor(a3, 32);
        if (sel == 0) {   // P = (S+D)/2
            ((float4*)Pout)[(size_t)row * 32 + q] =
                make_float4(0.5f * (a0 + b0), 0.5f * (a1 + b1),
                            0.5f * (a2 + b2), 0.5f * (a3 + b3));
        } else {          // M = (S-D)/2, here a=D, b=S
            ((float4*)Mout)[(size_t)row * 32 + q] =
                make_float4(0.5f * (b0 - a0), 0.5f * (b1 - a1),
                            0.5f * (b2 - a2), 0.5f * (b3 - a3));
        }
    }
}

extern "C" void kernel_launch(void* const* d_in, const int* in_sizes, int n_in,
                              void* d_out, int out_size, void* d_ws, size_t ws_size,
                              hipStream_t stream) {
    const int*   rows_p = (const int*)d_in[0];
    const int*   cols_p = (const int*)d_in[1];
    const float* vals_p = (const float*)d_in[2];
    const int*   rows_m = (const int*)d_in[3];
    const int*   cols_m = (const int*)d_in[4];
    const float* vals_m = (const float*)d_in[5];
    const float* X      = (const float*)d_in[6];
    const float* M0     = (const float*)d_in[7];

    const int E = in_sizes[0];
    const int D = 128;
    const int N = in_sizes[6] / D;       // 50000 (<65536: 16-bit r/c packing ok)
    const int K = 10;
    const int E2 = 2 * E;
    const size_t ND = (size_t)N * D;
    const int N32 = N * 32;
    const int NBv = (N + 511) >> 9;      // buckets of 512 rows, <=128

    float* outP = (float*)d_out;
    float* outM = outP + ND;

    char* ws = (char*)d_ws;
    size_t o = 0;
    auto alloc = [&](size_t b) -> void* {
        void* p = ws + o;
        o += (b + 255) & ~(size_t)255;
        return p;
    };
    uint2*    SDA  = (uint2*)alloc((size_t)N * 64 * 8);
    uint2*    SDB  = (uint2*)alloc((size_t)N * 64 * 8);
    uint2*    tXb  = (uint2*)alloc((size_t)N * 32 * 8);
    int*      off  = (int*)alloc((size_t)(N + 1) * sizeof(int));
    unsigned* edge = (unsigned*)alloc((size_t)E2 * sizeof(unsigned));
    int*      bcnt = (int*)alloc(128 * sizeof(int));
    int*      boff = (int*)alloc(129 * sizeof(int));
    int*      bcur = (int*)alloc(128 * sizeof(int));
    // stage aliases SDB: consumed by csr_finalize before layer 0 writes SDB.
    uint2* stage = SDB;

    int gN32 = (N32 + TB - 1) / TB;
    int gTiles = (E2 + 2047) / 2048;

    // --- CSR build: bucket partition with LDS write-combining ---
    zero_int_kernel<<<1, 128, 0, stream>>>(bcnt, 128);
    bucket_count_kernel<<<512, TB, 0, stream>>>(rows_p, rows_m, E, bcnt);
    bucket_scan_kernel<<<1, 64, 0, stream>>>(bcnt, boff, bcur);
    partition_kernel<<<gTiles, TB, 0, stream>>>(rows_p, cols_p, vals_p,
                                                rows_m, cols_m, vals_m, E,
                                                bcur, stage);
    csr_finalize_kernel<<<NBv, TB, 0, stream>>>(stage, boff, NBv, N, E2, off, edge);

    // --- init interleaved bf16 state ---
    init_kernel<<<gN32, TB, 0, stream>>>(X, M0, SDA, tXb, N32);

    // --- K layers, ping-pong; last layer writes fp32 P/M directly ---
    int gL = (N + 3) / 4;
    uint2 *Si = SDA, *So = SDB;
    for (int k = 0; k < K; ++k) {
        int last = (k == K - 1);
        layer_kernel<<<gL, TB, 0, stream>>>(off, edge, Si, So, tXb,
                                            outP, outM, last, N);
        uint2* t = Si; Si = So; So = t;
    }
}